// Round 1
// baseline (260.279 us; speedup 1.0000x reference)
//
#include <hip/hip_runtime.h>
#include <hip/hip_bf16.h>

// B=8, C=256, H=W=32, N=HW=1024.
// Pipeline (per batch), all GEMMs C[M,N] = A[M,K] · Bt[N,K]^T (both K-contiguous):
//  xT   = transpose(x) bf16                      [1024,256]
//  x1   = w1·xT^T + b1(row)                      [1024,1024]  (chan, hw)
//  x1T  = xT·w1^T + b1(col)                      [1024,1024]  (hw, chan)
//  gT   = x1T·wq^T + bq(col)                     [hw, gchan]
//  rT   = x1T·wv^T + bv(col)                     [hw, rchan]
//  S    = x1·gT^T (fp32)                         [chan, hw]   ; C2 = S^T (algebra)
//  zs   = alpha * row-softmax(S)      bf16       [i, k]
//  zc   = beta  * col-softmax(S)      bf16       [q, k]  (= row-softmax of S^T)
//  PT   = rT·zs^T + zc·x1^T           bf16       [hw, n]
//  out  = w2·PT^T + b2(row)           fp32       [256, 1024]
// Workspace: ~105 MB (with lifetime-based aliasing).

typedef __attribute__((ext_vector_type(4))) float f4;
typedef __attribute__((ext_vector_type(8))) short s8;
typedef __attribute__((ext_vector_type(4))) unsigned short us4;
typedef __attribute__((ext_vector_type(8))) unsigned short us8;

__device__ __forceinline__ unsigned short f2bf(float f) {
    __hip_bfloat16 h = __float2bfloat16(f);
    return __builtin_bit_cast(unsigned short, h);
}

#define GAS(p) ((const __attribute__((address_space(1))) unsigned int*)(p))
#define LAS(p) ((__attribute__((address_space(3))) unsigned int*)(p))

// ---------------- weight fp32 -> bf16 conversion (4 arrays fused) -------------
__global__ __launch_bounds__(256) void conv_weights(
    const float* __restrict__ w1, const float* __restrict__ wq,
    const float* __restrict__ wv, const float* __restrict__ w2,
    unsigned short* __restrict__ w1b, unsigned short* __restrict__ wqb,
    unsigned short* __restrict__ wvb, unsigned short* __restrict__ w2b)
{
    long i = (long)blockIdx.x * 256 + threadIdx.x;  // float4 index, total 655360
    const float* src; unsigned short* dst; long base;
    if (i < 65536)               { src = w1; dst = w1b; base = 0; }
    else if (i < 65536+262144)   { src = wq; dst = wqb; base = 65536; }
    else if (i < 65536+524288)   { src = wv; dst = wvb; base = 65536+262144; }
    else                         { src = w2; dst = w2b; base = 65536+524288; }
    long j = i - base;
    f4 v = ((const f4*)src)[j];
    us4 o;
    #pragma unroll
    for (int k = 0; k < 4; ++k) o[k] = f2bf(v[k]);
    ((us4*)dst)[j] = o;
}

// ---------------- x [8][256][1024] fp32 -> xT [8][1024][256] bf16 -------------
__global__ __launch_bounds__(256) void transpose_x(
    const float* __restrict__ x, unsigned short* __restrict__ xT)
{
    __shared__ float tl[32][33];
    const int b  = blockIdx.z;
    const int q0 = blockIdx.x * 32;
    const int c0 = blockIdx.y * 32;
    const int tx = threadIdx.x & 31, ty = threadIdx.x >> 5;  // ty 0..7
    #pragma unroll
    for (int j = 0; j < 4; ++j)
        tl[ty + j*8][tx] = x[((long)(b*256 + c0 + ty + j*8))*1024 + q0 + tx];
    __syncthreads();
    #pragma unroll
    for (int j = 0; j < 4; ++j)
        xT[((long)(b*1024 + q0 + ty + j*8))*256 + c0 + tx] = f2bf(tl[tx][ty + j*8]);
}

// ---------------- GEMM: C = A·Bt^T, 128x128 tile, BK=32, 4 waves --------------
// BIAS: 0 none, 1 row (bias[row]), 2 col (bias[col]). OUTF32: 1 fp32, 0 bf16.
template<int BIAS, int OUTF32>
__global__ __launch_bounds__(256) void gemm_bt(
    const unsigned short* __restrict__ A,  long sA,
    const unsigned short* __restrict__ Bt, long sB,
    void* __restrict__ Cv, long sC,
    const float* __restrict__ bias, int K, int ldc)
{
    __shared__ __align__(16) unsigned short As[4096];
    __shared__ __align__(16) unsigned short Bs[4096];

    const int b = blockIdx.z;
    const unsigned short* Ab  = A  + (long)b * sA;
    const unsigned short* Btb = Bt + (long)b * sB;
    const int m0 = blockIdx.y * 128;
    const int n0 = blockIdx.x * 128;

    const int t = threadIdx.x;
    const int w = t >> 6, l = t & 63;
    const int wr = w >> 1, wc = w & 1;
    const int lr = l & 15, kh = (l >> 4) * 8;

    f4 acc[4][4];
    #pragma unroll
    for (int i = 0; i < 4; ++i)
        #pragma unroll
        for (int j = 0; j < 4; ++j) acc[i][j] = (f4){0.f, 0.f, 0.f, 0.f};

    // staging: tile = 8 chunks of 1 KiB; wave w owns chunks 2w, 2w+1.
    const int c0 = w*2, c1 = w*2 + 1;
    const int e0 = c0*512 + l*8, e1 = c1*512 + l*8;   // bf16 element offset in tile
    const int r0 = e0 >> 5, ko0 = e0 & 31;
    const int r1 = e1 >> 5, ko1 = e1 & 31;

    for (int kt = 0; kt < K; kt += 32) {
        __builtin_amdgcn_global_load_lds(GAS(Ab  + (long)(m0 + r0)*K + kt + ko0), LAS(&As[c0*512]), 16, 0, 0);
        __builtin_amdgcn_global_load_lds(GAS(Ab  + (long)(m0 + r1)*K + kt + ko1), LAS(&As[c1*512]), 16, 0, 0);
        __builtin_amdgcn_global_load_lds(GAS(Btb + (long)(n0 + r0)*K + kt + ko0), LAS(&Bs[c0*512]), 16, 0, 0);
        __builtin_amdgcn_global_load_lds(GAS(Btb + (long)(n0 + r1)*K + kt + ko1), LAS(&Bs[c1*512]), 16, 0, 0);
        __syncthreads();

        s8 aF[4], bF[4];
        #pragma unroll
        for (int m = 0; m < 4; ++m) aF[m] = *(const s8*)&As[(wr*64 + m*16 + lr)*32 + kh];
        #pragma unroll
        for (int n = 0; n < 4; ++n) bF[n] = *(const s8*)&Bs[(wc*64 + n*16 + lr)*32 + kh];
        #pragma unroll
        for (int m = 0; m < 4; ++m)
            #pragma unroll
            for (int n = 0; n < 4; ++n)
                acc[m][n] = __builtin_amdgcn_mfma_f32_16x16x32_bf16(aF[m], bF[n], acc[m][n], 0, 0, 0);
        __syncthreads();
    }

    const int rbase = (l >> 4) * 4;
    #pragma unroll
    for (int m = 0; m < 4; ++m) {
        #pragma unroll
        for (int n = 0; n < 4; ++n) {
            const int row = m0 + wr*64 + m*16 + rbase;
            const int col = n0 + wc*64 + n*16 + lr;
            #pragma unroll
            for (int j = 0; j < 4; ++j) {
                float v = acc[m][n][j];
                if (BIAS == 1) v += bias[row + j];
                else if (BIAS == 2) v += bias[col];
                const long idx = (long)b*sC + (long)(row + j)*ldc + col;
                if (OUTF32) ((float*)Cv)[idx] = v;
                else ((unsigned short*)Cv)[idx] = f2bf(v);
            }
        }
    }
}

// ---------------- dual GEMM: C = A1·B1^T + A2·B2^T (1024^3, batched, bf16) ----
__global__ __launch_bounds__(256) void gemm_dual(
    const unsigned short* __restrict__ A1, const unsigned short* __restrict__ B1,
    const unsigned short* __restrict__ A2, const unsigned short* __restrict__ B2,
    unsigned short* __restrict__ C)
{
    __shared__ __align__(16) unsigned short As[4096];
    __shared__ __align__(16) unsigned short Bs[4096];

    const int b = blockIdx.z;
    const int m0 = blockIdx.y * 128;
    const int n0 = blockIdx.x * 128;
    const int t = threadIdx.x;
    const int w = t >> 6, l = t & 63;
    const int wr = w >> 1, wc = w & 1;
    const int lr = l & 15, kh = (l >> 4) * 8;

    f4 acc[4][4];
    #pragma unroll
    for (int i = 0; i < 4; ++i)
        #pragma unroll
        for (int j = 0; j < 4; ++j) acc[i][j] = (f4){0.f, 0.f, 0.f, 0.f};

    const int c0 = w*2, c1 = w*2 + 1;
    const int e0 = c0*512 + l*8, e1 = c1*512 + l*8;
    const int r0 = e0 >> 5, ko0 = e0 & 31;
    const int r1 = e1 >> 5, ko1 = e1 & 31;

    for (int pass = 0; pass < 2; ++pass) {
        const unsigned short* Ab = (pass ? A2 : A1) + (long)b * 1048576;
        const unsigned short* Bb = (pass ? B2 : B1) + (long)b * 1048576;
        for (int kt = 0; kt < 1024; kt += 32) {
            __builtin_amdgcn_global_load_lds(GAS(Ab + (long)(m0 + r0)*1024 + kt + ko0), LAS(&As[c0*512]), 16, 0, 0);
            __builtin_amdgcn_global_load_lds(GAS(Ab + (long)(m0 + r1)*1024 + kt + ko1), LAS(&As[c1*512]), 16, 0, 0);
            __builtin_amdgcn_global_load_lds(GAS(Bb + (long)(n0 + r0)*1024 + kt + ko0), LAS(&Bs[c0*512]), 16, 0, 0);
            __builtin_amdgcn_global_load_lds(GAS(Bb + (long)(n0 + r1)*1024 + kt + ko1), LAS(&Bs[c1*512]), 16, 0, 0);
            __syncthreads();

            s8 aF[4], bF[4];
            #pragma unroll
            for (int m = 0; m < 4; ++m) aF[m] = *(const s8*)&As[(wr*64 + m*16 + lr)*32 + kh];
            #pragma unroll
            for (int n = 0; n < 4; ++n) bF[n] = *(const s8*)&Bs[(wc*64 + n*16 + lr)*32 + kh];
            #pragma unroll
            for (int m = 0; m < 4; ++m)
                #pragma unroll
                for (int n = 0; n < 4; ++n)
                    acc[m][n] = __builtin_amdgcn_mfma_f32_16x16x32_bf16(aF[m], bF[n], acc[m][n], 0, 0, 0);
            __syncthreads();
        }
    }

    const int rbase = (l >> 4) * 4;
    #pragma unroll
    for (int m = 0; m < 4; ++m) {
        #pragma unroll
        for (int n = 0; n < 4; ++n) {
            const int row = m0 + wr*64 + m*16 + rbase;
            const int col = n0 + wc*64 + n*16 + lr;
            #pragma unroll
            for (int j = 0; j < 4; ++j)
                C[(long)b*1048576 + (long)(row + j)*1024 + col] = f2bf(acc[m][n][j]);
        }
    }
}

// ---------------- row softmax: zs[r][k] = scale * softmax_k(S[r][k]) ----------
__global__ __launch_bounds__(256) void row_softmax(
    const float* __restrict__ S, unsigned short* __restrict__ Z,
    const float* __restrict__ scale_p)
{
    const int wid = threadIdx.x >> 6, l = threadIdx.x & 63;
    const long row = (long)blockIdx.x * 4 + wid;   // 8192 rows total
    const float* src = S + row * 1024;
    f4 v[4];
    #pragma unroll
    for (int i = 0; i < 4; ++i) v[i] = *(const f4*)&src[(i*64 + l)*4];
    float m = -3.4e38f;
    #pragma unroll
    for (int i = 0; i < 4; ++i)
        #pragma unroll
        for (int j = 0; j < 4; ++j) m = fmaxf(m, v[i][j]);
    #pragma unroll
    for (int off = 32; off; off >>= 1) m = fmaxf(m, __shfl_xor(m, off));
    float s = 0.f;
    #pragma unroll
    for (int i = 0; i < 4; ++i)
        #pragma unroll
        for (int j = 0; j < 4; ++j) { v[i][j] = __expf(v[i][j] - m); s += v[i][j]; }
    #pragma unroll
    for (int off = 32; off; off >>= 1) s += __shfl_xor(s, off);
    const float c = scale_p[0] / s;
    #pragma unroll
    for (int i = 0; i < 4; ++i) {
        us4 o;
        #pragma unroll
        for (int j = 0; j < 4; ++j) o[j] = f2bf(v[i][j] * c);
        *(us4*)&Z[row*1024 + (long)(i*64 + l)*4] = o;
    }
}

// ---------------- col softmax: zc[q][k] = scale * exp(S[k][q]-max)/sum --------
__global__ __launch_bounds__(256) void col_softmax(
    const float* __restrict__ S, unsigned short* __restrict__ Z,
    const float* __restrict__ scale_p)
{
    __shared__ float part[8][32];
    const int b  = blockIdx.y;
    const int ci = threadIdx.x & 31;
    const int ks = threadIdx.x >> 5;          // k-slice 0..7 (128 rows each)
    const int q  = blockIdx.x * 32 + ci;
    const float* Sb = S + (long)b * 1048576;

    float m = -3.4e38f;
    for (int k = ks*128; k < ks*128 + 128; ++k) m = fmaxf(m, Sb[(long)k*1024 + q]);
    part[ks][ci] = m;
    __syncthreads();
    if (ks == 0) {
        float mm = part[0][ci];
        #pragma unroll
        for (int i = 1; i < 8; ++i) mm = fmaxf(mm, part[i][ci]);
        part[0][ci] = mm;
    }
    __syncthreads();
    m = part[0][ci];
    __syncthreads();
    float s = 0.f;
    for (int k = ks*128; k < ks*128 + 128; ++k) s += __expf(Sb[(long)k*1024 + q] - m);
    part[ks][ci] = s;
    __syncthreads();
    float stot = 0.f;
    #pragma unroll
    for (int i = 0; i < 8; ++i) stot += part[i][ci];
    const float c = scale_p[0] / stot;

    unsigned short* Zb = Z + (long)b*1048576 + (long)q*1024;
    for (int kc = 0; kc < 16; ++kc) {
        us8 o;
        #pragma unroll
        for (int j = 0; j < 8; ++j)
            o[j] = f2bf(c * __expf(Sb[(long)(ks*128 + kc*8 + j)*1024 + q] - m));
        *(us8*)&Zb[ks*128 + kc*8] = o;
    }
}

// -----------------------------------------------------------------------------
extern "C" void kernel_launch(void* const* d_in, const int* in_sizes, int n_in,
                              void* d_out, int out_size, void* d_ws, size_t ws_size,
                              hipStream_t stream)
{
    const float* x     = (const float*)d_in[0];
    const float* w1    = (const float*)d_in[1];
    const float* b1    = (const float*)d_in[2];
    const float* wq    = (const float*)d_in[3];
    const float* bq    = (const float*)d_in[4];
    const float* wv    = (const float*)d_in[5];
    const float* bv    = (const float*)d_in[6];
    const float* w2    = (const float*)d_in[7];
    const float* b2    = (const float*)d_in[8];
    const float* alpha = (const float*)d_in[9];
    const float* beta  = (const float*)d_in[10];
    float* out = (float*)d_out;

    char* ws = (char*)d_ws;
    size_t off = 0;
    auto alloc = [&](size_t bytes) -> void* {
        void* p = ws + off; off += (bytes + 255) & ~(size_t)255; return p;
    };
    unsigned short* xTb  = (unsigned short*)alloc(8L*1024*256*2);    //  4 MB
    unsigned short* w1b  = (unsigned short*)alloc(1024L*256*2);      // .5 MB
    unsigned short* wqb  = (unsigned short*)alloc(1024L*1024*2);     //  2 MB
    unsigned short* wvb  = (unsigned short*)alloc(1024L*1024*2);     //  2 MB
    unsigned short* w2b  = (unsigned short*)alloc(256L*1024*2);      // .5 MB
    unsigned short* x1b  = (unsigned short*)alloc(8L*1024*1024*2);   // 16 MB
    unsigned short* x1tb = (unsigned short*)alloc(8L*1024*1024*2);   // 16 MB
    unsigned short* gtb  = (unsigned short*)alloc(8L*1024*1024*2);   // 16 MB
    unsigned short* rtb  = (unsigned short*)alloc(8L*1024*1024*2);   // 16 MB
    float*          Sf   = (float*)alloc(8L*1024*1024*4);            // 32 MB
    // lifetime-based aliases:
    unsigned short* zsb  = x1tb;               // x1tb dead after rT GEMM
    unsigned short* zcb  = gtb;                // gtb dead after S GEMM
    unsigned short* Ptb  = (unsigned short*)Sf; // Sf dead after softmaxes

    const long S1M = 1048576;

    conv_weights<<<2560, 256, 0, stream>>>(w1, wq, wv, w2, w1b, wqb, wvb, w2b);
    transpose_x<<<dim3(32, 8, 8), 256, 0, stream>>>(x, xTb);

    // x1 = w1·xT^T + b1(row)        [chan, hw]
    gemm_bt<1,0><<<dim3(8, 8, 8), 256, 0, stream>>>(w1b, 0, xTb, 262144, x1b, S1M, b1, 256, 1024);
    // x1T = xT·w1^T + b1(col)       [hw, chan]
    gemm_bt<2,0><<<dim3(8, 8, 8), 256, 0, stream>>>(xTb, 262144, w1b, 0, x1tb, S1M, b1, 256, 1024);
    // gT = x1T·wq^T + bq(col)       [hw, gchan]
    gemm_bt<2,0><<<dim3(8, 8, 8), 256, 0, stream>>>(x1tb, S1M, wqb, 0, gtb, S1M, bq, 1024, 1024);
    // rT = x1T·wv^T + bv(col)       [hw, rchan]
    gemm_bt<2,0><<<dim3(8, 8, 8), 256, 0, stream>>>(x1tb, S1M, wvb, 0, rtb, S1M, bv, 1024, 1024);
    // S = x1·gT^T (fp32)            [chan, hw]
    gemm_bt<0,1><<<dim3(8, 8, 8), 256, 0, stream>>>(x1b, S1M, gtb, S1M, Sf, S1M, nullptr, 1024, 1024);
    // zs = alpha * row-softmax(S); zc = beta * col-softmax(S)  (C2 = S^T)
    row_softmax<<<2048, 256, 0, stream>>>(Sf, zsb, alpha);
    col_softmax<<<dim3(32, 8), 256, 0, stream>>>(Sf, zcb, beta);
    // PT = rT·zs^T + zc·x1^T        [hw, n]
    gemm_dual<<<dim3(8, 8, 8), 256, 0, stream>>>(rtb, zsb, zcb, x1b, Ptb);
    // out = w2·PT^T + b2(row), fp32 [256, 1024]
    gemm_bt<1,1><<<dim3(8, 2, 8), 256, 0, stream>>>(w2b, 0, Ptb, S1M, out, 262144, b2, 1024, 1024);
}

// Round 2
// 215.246 us; speedup vs baseline: 1.2092x; 1.2092x over previous
//
#include <hip/hip_runtime.h>
#include <hip/hip_bf16.h>

// B=8, C=256, H=W=32, N=HW=1024.
// Pipeline (all GEMMs C[M,N] = A[M,K] · Bt[N,K]^T, both K-contiguous):
//  xT    = transpose(x) bf16                      [8][1024,256]
//  x1    = w1·xT^T + b1(row)                      [8][chan,hw]
//  x1T   = xT·w1^T + b1(col)   (stacked M=8192)   [8][hw,chan]
//  gT|rT = x1T·(wq||wv)^T + (bq||bv)(col)  stacked M=8192, N=2048, split out
//  S     = x1·gT^T (fp32)                         [8][chan,hw] ; C2 = S^T (algebra)
//  zs    = alpha * row-softmax(S)      bf16  -> x1tb (dead)
//  zc    = beta  * col-softmax(S)      bf16  -> gtb  (dead)
//  PT    = rT·zs^T + zc·x1^T           bf16  -> Sf   (dead)
//  out   = w2·PT^T + b2(row)           fp32
// GEMM core: 128x128 tile, BK=32, 4 waves, 3-buffer depth-2 counted-vmcnt
// pipeline, XOR bank swizzle (chunk ^= (row>>1)&3 on both stage-src and read).

typedef __attribute__((ext_vector_type(4))) float f4;
typedef __attribute__((ext_vector_type(8))) short s8;
typedef __attribute__((ext_vector_type(4))) unsigned short us4;
typedef __attribute__((ext_vector_type(8))) unsigned short us8;

__device__ __forceinline__ unsigned short f2bf(float f) {
    __hip_bfloat16 h = __float2bfloat16(f);
    return __builtin_bit_cast(unsigned short, h);
}

#define GAS(p) ((const __attribute__((address_space(1))) unsigned int*)(p))
#define LAS(p) ((__attribute__((address_space(3))) unsigned int*)(p))

// ---------------- weight fp32 -> bf16 conversion + bias concat ----------------
__global__ __launch_bounds__(256) void conv_weights(
    const float* __restrict__ w1, const float* __restrict__ wq,
    const float* __restrict__ wv, const float* __restrict__ w2,
    unsigned short* __restrict__ w1b, unsigned short* __restrict__ wqb,
    unsigned short* __restrict__ wvb, unsigned short* __restrict__ w2b,
    const float* __restrict__ bq, const float* __restrict__ bv,
    float* __restrict__ biasqv)
{
    long i = (long)blockIdx.x * 256 + threadIdx.x;  // float4 index
    if (i >= 655360) {                               // bias concat: 512 f4
        long j = i - 655360;
        if (j < 512) {
            f4 v = (j < 256) ? ((const f4*)bq)[j] : ((const f4*)bv)[j - 256];
            ((f4*)biasqv)[j] = v;
        }
        return;
    }
    const float* src; unsigned short* dst; long base;
    if (i < 65536)               { src = w1; dst = w1b; base = 0; }
    else if (i < 65536+262144)   { src = wq; dst = wqb; base = 65536; }
    else if (i < 65536+524288)   { src = wv; dst = wvb; base = 65536+262144; }
    else                         { src = w2; dst = w2b; base = 65536+524288; }
    long j = i - base;
    f4 v = ((const f4*)src)[j];
    us4 o;
    #pragma unroll
    for (int k = 0; k < 4; ++k) o[k] = f2bf(v[k]);
    ((us4*)dst)[j] = o;
}

// ---------------- x [8][256][1024] fp32 -> xT [8][1024][256] bf16 -------------
__global__ __launch_bounds__(256) void transpose_x(
    const float* __restrict__ x, unsigned short* __restrict__ xT)
{
    __shared__ float tl[32][33];
    const int b  = blockIdx.z;
    const int q0 = blockIdx.x * 32;
    const int c0 = blockIdx.y * 32;
    const int tx = threadIdx.x & 31, ty = threadIdx.x >> 5;  // ty 0..7
    #pragma unroll
    for (int j = 0; j < 4; ++j)
        tl[ty + j*8][tx] = x[((long)(b*256 + c0 + ty + j*8))*1024 + q0 + tx];
    __syncthreads();
    #pragma unroll
    for (int j = 0; j < 4; ++j)
        xT[((long)(b*1024 + q0 + ty + j*8))*256 + c0 + tx] = f2bf(tl[tx][ty + j*8]);
}

// ---------------- pipelined GEMM core -----------------------------------------
// BIAS: 0 none, 1 row, 2 col. OUTF32: fp32 out. SPLIT: cols>=1024 -> Cv1.
// NPASS: 1 or 2 (dual acc). NT1: K-steps per pass (K = NT1*32).
template<int BIAS, int OUTF32, int SPLIT, int NPASS, int NT1>
__global__ __launch_bounds__(256) void gemm_pipe(
    const unsigned short* __restrict__ A0, const unsigned short* __restrict__ Bt0,
    const unsigned short* __restrict__ A1, const unsigned short* __restrict__ Bt1,
    long sA, long sB, int lda, int ldb,
    void* __restrict__ Cv0, void* __restrict__ Cv1, long sC, int ldc,
    const float* __restrict__ bias)
{
    constexpr int NT = NPASS * NT1;
    __shared__ __align__(16) unsigned short As[3][4096];
    __shared__ __align__(16) unsigned short Bs[3][4096];

    const int b  = blockIdx.z;
    const int m0 = blockIdx.y * 128;
    const int n0 = blockIdx.x * 128;
    const int t  = threadIdx.x;
    const int w  = t >> 6, l = t & 63;
    const int wr = w >> 1, wc = w & 1;
    const int lr = l & 15;

    const unsigned short* A0b  = A0  + (long)b * sA;
    const unsigned short* B0b  = Bt0 + (long)b * sB;
    const unsigned short* A1b  = (NPASS > 1) ? A1  + (long)b * sA : nullptr;
    const unsigned short* B1b  = (NPASS > 1) ? Bt1 + (long)b * sB : nullptr;

    // staging geometry: tile = 8 x 1KiB chunks; wave w owns chunks 2w, 2w+1.
    // lane l writes LDS slot (row rA + {0,16}, chunk cs=l&3); fetches global
    // chunk c = cs ^ ((row>>1)&3) = (l&3) ^ ((l>>3)&3)  [pre-swizzled source].
    const int rA   = w*32 + (l >> 2);
    const int cswz = ((l & 3) ^ ((l >> 3) & 3)) * 8;

    // read-side swizzle: chunk addr = (l>>4) ^ ((lr>>1)&3)
    const int swzr = (((l >> 4) ^ ((lr >> 1) & 3)) * 8);

    f4 acc[4][4];
    #pragma unroll
    for (int i = 0; i < 4; ++i)
        #pragma unroll
        for (int j = 0; j < 4; ++j) acc[i][j] = (f4){0.f, 0.f, 0.f, 0.f};

    auto stage = [&](int sp, int bf) {
        const unsigned short* Ap; const unsigned short* Bp; int kt;
        if (NPASS > 1 && sp >= NT1) { Ap = A1b; Bp = B1b; kt = (sp - NT1) * 32; }
        else                        { Ap = A0b; Bp = B0b; kt = sp * 32; }
        __builtin_amdgcn_global_load_lds(GAS(Ap + (long)(m0 + rA     )*lda + kt + cswz), LAS(&As[bf][w*1024      ]), 16, 0, 0);
        __builtin_amdgcn_global_load_lds(GAS(Ap + (long)(m0 + rA + 16)*lda + kt + cswz), LAS(&As[bf][w*1024 + 512]), 16, 0, 0);
        __builtin_amdgcn_global_load_lds(GAS(Bp + (long)(n0 + rA     )*ldb + kt + cswz), LAS(&Bs[bf][w*1024      ]), 16, 0, 0);
        __builtin_amdgcn_global_load_lds(GAS(Bp + (long)(n0 + rA + 16)*ldb + kt + cswz), LAS(&Bs[bf][w*1024 + 512]), 16, 0, 0);
    };

    stage(0, 0);
    stage(1, 1);

    int buf = 0;
    for (int s = 0; s < NT; ++s) {
        if (s + 1 < NT) asm volatile("s_waitcnt vmcnt(4)" ::: "memory");
        else            asm volatile("s_waitcnt vmcnt(0)" ::: "memory");
        __builtin_amdgcn_s_barrier();
        __builtin_amdgcn_sched_barrier(0);

        s8 aF[4], bF[4];
        #pragma unroll
        for (int m = 0; m < 4; ++m) aF[m] = *(const s8*)&As[buf][(wr*64 + m*16 + lr)*32 + swzr];
        #pragma unroll
        for (int n = 0; n < 4; ++n) bF[n] = *(const s8*)&Bs[buf][(wc*64 + n*16 + lr)*32 + swzr];

        if (s + 2 < NT) { int bn = buf + 2; if (bn >= 3) bn -= 3; stage(s + 2, bn); }

        __builtin_amdgcn_s_setprio(1);
        #pragma unroll
        for (int m = 0; m < 4; ++m)
            #pragma unroll
            for (int n = 0; n < 4; ++n)
                acc[m][n] = __builtin_amdgcn_mfma_f32_16x16x32_bf16(aF[m], bF[n], acc[m][n], 0, 0, 0);
        __builtin_amdgcn_s_setprio(0);

        if (++buf == 3) buf = 0;
    }

    void* Cd = Cv0; int nbase = n0;
    if (SPLIT && n0 >= 1024) { Cd = Cv1; nbase = n0 - 1024; }

    const int rbase = (l >> 4) * 4;
    #pragma unroll
    for (int m = 0; m < 4; ++m) {
        #pragma unroll
        for (int n = 0; n < 4; ++n) {
            const int row  = m0 + wr*64 + m*16 + rbase;
            const int col  = nbase + wc*64 + n*16 + lr;
            const int bcol = n0    + wc*64 + n*16 + lr;
            #pragma unroll
            for (int j = 0; j < 4; ++j) {
                float v = acc[m][n][j];
                if (BIAS == 1) v += bias[row + j];
                else if (BIAS == 2) v += bias[bcol];
                const long idx = (long)b*sC + (long)(row + j)*ldc + col;
                if (OUTF32) ((float*)Cd)[idx] = v;
                else ((unsigned short*)Cd)[idx] = f2bf(v);
            }
        }
    }
}

// ---------------- row softmax: zs[r][k] = scale * softmax_k(S[r][k]) ----------
__global__ __launch_bounds__(256) void row_softmax(
    const float* __restrict__ S, unsigned short* __restrict__ Z,
    const float* __restrict__ scale_p)
{
    const int wid = threadIdx.x >> 6, l = threadIdx.x & 63;
    const long row = (long)blockIdx.x * 4 + wid;   // 8192 rows total
    const float* src = S + row * 1024;
    f4 v[4];
    #pragma unroll
    for (int i = 0; i < 4; ++i) v[i] = *(const f4*)&src[(i*64 + l)*4];
    float m = -3.4e38f;
    #pragma unroll
    for (int i = 0; i < 4; ++i)
        #pragma unroll
        for (int j = 0; j < 4; ++j) m = fmaxf(m, v[i][j]);
    #pragma unroll
    for (int off = 32; off; off >>= 1) m = fmaxf(m, __shfl_xor(m, off));
    float s = 0.f;
    #pragma unroll
    for (int i = 0; i < 4; ++i)
        #pragma unroll
        for (int j = 0; j < 4; ++j) { v[i][j] = __expf(v[i][j] - m); s += v[i][j]; }
    #pragma unroll
    for (int off = 32; off; off >>= 1) s += __shfl_xor(s, off);
    const float c = scale_p[0] / s;
    #pragma unroll
    for (int i = 0; i < 4; ++i) {
        us4 o;
        #pragma unroll
        for (int j = 0; j < 4; ++j) o[j] = f2bf(v[i][j] * c);
        *(us4*)&Z[row*1024 + (long)(i*64 + l)*4] = o;
    }
}

// ---------------- column stats: online max+sum per column ---------------------
__global__ __launch_bounds__(256) void col_stats(
    const float* __restrict__ S, float* __restrict__ cm, float* __restrict__ cs)
{
    __shared__ float pm[4][64], ps[4][64];
    const int b  = blockIdx.y;
    const int ci = threadIdx.x & 63, ks = threadIdx.x >> 6;
    const int q  = blockIdx.x * 64 + ci;
    const float* Sb = S + (long)b * 1048576 + q;
    float m = -3.4e38f, s = 0.f;
    for (int k = ks*256; k < ks*256 + 256; ++k) {
        float v = Sb[(long)k * 1024];
        float d = v - m;
        float ed = __expf(-fabsf(d));
        if (d > 0.f) { s = s * ed + 1.f; m = v; } else s += ed;
    }
    pm[ks][ci] = m; ps[ks][ci] = s;
    __syncthreads();
    if (threadIdx.x < 64) {
        float M = pm[0][ci];
        #pragma unroll
        for (int i = 1; i < 4; ++i) M = fmaxf(M, pm[i][ci]);
        float Ssum = 0.f;
        #pragma unroll
        for (int i = 0; i < 4; ++i) Ssum += ps[i][ci] * __expf(pm[i][ci] - M);
        cm[b*1024 + q] = M;
        cs[b*1024 + q] = Ssum;
    }
}

// ---------------- column softmax write: zc[q][k] = sc*exp(S[k][q]-m)/s --------
__global__ __launch_bounds__(256) void col_write(
    const float* __restrict__ S, const float* __restrict__ cm,
    const float* __restrict__ cs, unsigned short* __restrict__ Z,
    const float* __restrict__ scale_p)
{
    const int b  = blockIdx.z;
    const int k0 = blockIdx.y * 64;
    const int q  = blockIdx.x * 256 + threadIdx.x;
    const float m   = cm[b*1024 + q];
    const float inv = scale_p[0] / cs[b*1024 + q];
    const float* Sb = S + (long)b * 1048576 + q;
    unsigned short* Zb = Z + (long)b * 1048576 + (long)q * 1024 + k0;
    #pragma unroll
    for (int c8 = 0; c8 < 8; ++c8) {
        us8 o;
        #pragma unroll
        for (int j = 0; j < 8; ++j)
            o[j] = f2bf(inv * __expf(Sb[(long)(k0 + c8*8 + j) * 1024] - m));
        *(us8*)&Zb[c8*8] = o;
    }
}

// -----------------------------------------------------------------------------
extern "C" void kernel_launch(void* const* d_in, const int* in_sizes, int n_in,
                              void* d_out, int out_size, void* d_ws, size_t ws_size,
                              hipStream_t stream)
{
    const float* x     = (const float*)d_in[0];
    const float* w1    = (const float*)d_in[1];
    const float* b1    = (const float*)d_in[2];
    const float* wq    = (const float*)d_in[3];
    const float* bq    = (const float*)d_in[4];
    const float* wv    = (const float*)d_in[5];
    const float* bv    = (const float*)d_in[6];
    const float* w2    = (const float*)d_in[7];
    const float* b2    = (const float*)d_in[8];
    const float* alpha = (const float*)d_in[9];
    const float* beta  = (const float*)d_in[10];
    float* out = (float*)d_out;

    char* ws = (char*)d_ws;
    size_t off = 0;
    auto alloc = [&](size_t bytes) -> void* {
        void* p = ws + off; off += (bytes + 255) & ~(size_t)255; return p;
    };
    unsigned short* w1b   = (unsigned short*)alloc(1024L*256*2);      // .5 MB
    unsigned short* wqvb  = (unsigned short*)alloc(2048L*1024*2);     //  4 MB (wq||wv)
    unsigned short* w2b   = (unsigned short*)alloc(256L*1024*2);      // .5 MB
    float*          biasqv= (float*)alloc(2048L*4);                   //  8 KB
    float*          cmv   = (float*)alloc(8L*1024*4);                 // 32 KB
    float*          csv   = (float*)alloc(8L*1024*4);                 // 32 KB
    unsigned short* xTb   = (unsigned short*)alloc(8L*1024*256*2);    //  4 MB
    unsigned short* x1b   = (unsigned short*)alloc(8L*1024*1024*2);   // 16 MB
    unsigned short* x1tb  = (unsigned short*)alloc(8L*1024*1024*2);   // 16 MB
    unsigned short* gtb   = (unsigned short*)alloc(8L*1024*1024*2);   // 16 MB
    unsigned short* rtb   = (unsigned short*)alloc(8L*1024*1024*2);   // 16 MB
    float*          Sf    = (float*)alloc(8L*1024*1024*4);            // 32 MB
    // lifetime aliases:
    unsigned short* zsb = x1tb;                 // x1tb dead after gT/rT GEMM
    unsigned short* zcb = gtb;                  // gtb dead after S GEMM
    unsigned short* Ptb = (unsigned short*)Sf;  // Sf dead after softmaxes

    const long S1M = 1048576;

    conv_weights<<<2562, 256, 0, stream>>>(w1, wq, wv, w2, w1b, wqvb, wqvb + S1M, w2b, bq, bv, biasqv);
    transpose_x<<<dim3(32, 8, 8), 256, 0, stream>>>(x, xTb);

    // x1 = w1·xT^T + b1(row)               [8][chan,hw], z-batched
    gemm_pipe<1,0,0,1,8><<<dim3(8, 8, 8), 256, 0, stream>>>(
        w1b, xTb, nullptr, nullptr, 0, 262144, 256, 256, x1b, nullptr, S1M, 1024, b1);
    // x1T = xT·w1^T + b1(col)              stacked M=8192
    gemm_pipe<2,0,0,1,8><<<dim3(8, 64, 1), 256, 0, stream>>>(
        xTb, w1b, nullptr, nullptr, 0, 0, 256, 256, x1tb, nullptr, 0, 1024, b1);
    // gT|rT = x1T·(wq||wv)^T + bias(col)   stacked M=8192, N=2048, split output
    gemm_pipe<2,0,1,1,32><<<dim3(16, 64, 1), 256, 0, stream>>>(
        x1tb, wqvb, nullptr, nullptr, 0, 0, 1024, 1024, gtb, rtb, 0, 1024, biasqv);
    // S = x1·gT^T (fp32)                   z-batched
    gemm_pipe<0,1,0,1,32><<<dim3(8, 8, 8), 256, 0, stream>>>(
        x1b, gtb, nullptr, nullptr, S1M, S1M, 1024, 1024, Sf, nullptr, S1M, 1024, nullptr);
    // zs = alpha * row-softmax(S); zc = beta * col-softmax(S)   (C2 = S^T)
    row_softmax<<<2048, 256, 0, stream>>>(Sf, zsb, alpha);
    col_stats<<<dim3(16, 8), 256, 0, stream>>>(Sf, cmv, csv);
    col_write<<<dim3(4, 16, 8), 256, 0, stream>>>(Sf, cmv, csv, zcb, beta);
    // PT = rT·zs^T + zc·x1^T               dual-pass accumulate
    gemm_pipe<0,0,0,2,32><<<dim3(8, 8, 8), 256, 0, stream>>>(
        rtb, zsb, zcb, x1b, S1M, S1M, 1024, 1024, Ptb, nullptr, S1M, 1024, nullptr);
    // out = w2·PT^T + b2(row), fp32
    gemm_pipe<1,1,0,1,32><<<dim3(8, 2, 8), 256, 0, stream>>>(
        w2b, Ptb, nullptr, nullptr, 0, S1M, 1024, 1024, out, nullptr, 262144, 1024, b2);
}